// Round 7
// baseline (32.691 us; speedup 1.0000x reference)
//
#include <hip/hip_runtime.h>

typedef float f32x4 __attribute__((ext_vector_type(4)));

constexpr int B_ = 4;
constexpr int L_ = 4096;
constexpr int D_ = 128;
constexpr int K_ = 16;
constexpr int NKEY = 2 * K_;              // 32 candidates max
constexpr int QPB = 8;                    // queries per block
constexpr int BLOCKS = B_ * L_ / QPB;     // 2048 = 8 blocks/CU, one round
constexpr int SROWS = 38;                 // staged rows [i0-15, i0+22]
constexpr int SF4   = SROWS * (D_ / 4);   // 1216 float4 = 19456 B

static __device__ __forceinline__ int imin(int a, int b) { return a < b ? a : b; }
static __device__ __forceinline__ int imax(int a, int b) { return a > b ? a : b; }

// Fused, LDS-staged. Per block (8 consecutive queries):
//  - lanes 0..7 of wave 0: exact top-K search per lane using the PROVEN
//    greedy two-pointer (adds the 16-smallest distance multiset one element
//    at a time) + left tie-run + 32-key bitonic sort by key (dist<<12)|idx
//    == jax.lax.top_k (dist, index) order.  [round-5's "leftmost min-T
//    window" was WRONG: left duplicates tying at T can displace a strictly
//    closer right element.]
//  - threads 64..255 concurrently stage attr rows [i0-15, i0+22] into LDS
//    (superset of all window rows: window[i] is 16 wide and contains i).
//  - after one barrier, 256 threads stream 128 rows x 512 B from LDS
//    (global fallback only for rare tie-run rows left of the staged range).
__global__ __launch_bounds__(256, 8) void fused_nbr_kernel(
    const int* __restrict__ fi, const float* __restrict__ attr,
    float* __restrict__ out_dist, float* __restrict__ out_attr)
{
    __shared__ f32x4 s_attr[SF4];
    __shared__ int   s_nbr[QPB * K_];

    const int bid  = blockIdx.x;
    const int sbid = (bid & 7) * (BLOCKS / 8) + (bid >> 3);  // XCD-contiguous
    const int q0   = sbid * QPB;
    const int b    = q0 >> 12;
    const int i0   = q0 & (L_ - 1);
    const int* __restrict__ c = fi + b * L_;
    const f32x4* __restrict__ ab = (const f32x4*)(attr + (size_t)b * L_ * D_);
    const int tid = threadIdx.x;

    if (tid >= 64) {
        // ---- stage candidate attr rows into LDS (waves 1-3, coalesced) ----
        const int u0 = tid - 64;
        #pragma unroll
        for (int it = 0; it < 7; ++it) {
            int u = u0 + it * 192;
            if (u < SF4) {
                int r = u >> 5, off = u & 31;
                int g = imax(0, imin(L_ - 1, i0 - 15 + r));
                s_attr[u] = ab[(size_t)g * 32 + off];
            }
        }
    } else if (tid < QPB) {
        // ---- exact top-K search, one query per lane (greedy, proven) ----
        const int i  = i0 + tid;
        const int ci = c[i];

        // greedy two-pointer: 16-wide window holding the 16-smallest
        // distance multiset (contains ALL elements with dist < T)
        int lo = i, hi = i;
        #pragma unroll
        for (int t = 0; t < K_ - 1; ++t) {
            int dl = (lo > 0)      ? (ci - c[lo - 1]) : 0x7FFFFFFF;
            int dr = (hi < L_ - 1) ? (c[hi + 1] - ci) : 0x7FFFFFFF;
            if (dl <= dr) --lo; else ++hi;
        }
        const int T = imax(ci - c[lo], c[hi] - ci);

        // key = (dist<<12)|idx : ascending key == ascending (dist, idx),
        // exactly jax.lax.top_k tie-breaking (dist < 2^18, idx < 2^12).
        int keys[NKEY];
        #pragma unroll
        for (int t = 0; t < K_; ++t) {
            int j = lo + t;
            int v = c[j];
            int d = (v < ci) ? (ci - v) : (v - ci);
            keys[t] = (d << 12) | j;
        }

        // left tie-run (value ci-T, indices < lo) can win the tie-break
        const int vL = ci - T;
        int j0 = -1;
        if (c[lo] == vL) j0 = lo;
        else if (lo > 0 && c[lo - 1] == vL) j0 = lo - 1;
        #pragma unroll
        for (int t = 0; t < K_; ++t) keys[K_ + t] = 0x7FFFFFFF;
        if (j0 >= 0) {
            int p = j0;
            while (p > 0 && c[p - 1] == vL) --p;     // run start (min index)
            const int e = imin(lo - 1, p + (K_ - 1));
            #pragma unroll
            for (int t = 0; t < K_; ++t) {
                int j = p + t;
                if (j <= e) keys[K_ + t] = (T << 12) | j;
            }
        }

        // bitonic sort, 32 keys, fully unrolled (registers only)
        #pragma unroll
        for (int size = 2; size <= NKEY; size <<= 1) {
            #pragma unroll
            for (int stride = size >> 1; stride > 0; stride >>= 1) {
                #pragma unroll
                for (int x = 0; x < NKEY; ++x) {
                    int y = x ^ stride;
                    if (y > x) {
                        bool up = ((x & size) == 0);
                        int a = keys[x], bb = keys[y];
                        int mn = imin(a, bb), mx = imax(a, bb);
                        keys[x] = up ? mn : mx;
                        keys[y] = up ? mx : mn;
                    }
                }
            }
        }

        // emit: neighbor rows -> LDS, distances -> out_dist (exact float)
        float* od = out_dist + (size_t)(q0 + tid) * K_;
        #pragma unroll
        for (int t = 0; t < K_; ++t) {
            s_nbr[tid * K_ + t] = keys[t] & (L_ - 1);
            od[t] = (float)(keys[t] >> 12);
        }
    }
    __syncthreads();

    // ---- streaming gather: 128 rows x 512 B from LDS, contiguous stores ----
    f32x4* __restrict__ dst = (f32x4*)out_attr + (size_t)q0 * (K_ * D_ / 4);
    const int lane = tid & 31, grp = tid >> 5;
    #pragma unroll 8
    for (int it = 0; it < 16; ++it) {
        int row = it * 8 + grp;                 // q_local*16 + k
        int j  = s_nbr[row];
        int lr = j - (i0 - 15);
        f32x4 val;
        if (__builtin_expect((unsigned)lr < (unsigned)SROWS, 1))
            val = s_attr[lr * 32 + lane];
        else                                    // rare: tie-run row left of range
            val = ab[(size_t)j * 32 + lane];
        dst[(size_t)row * 32 + lane] = val;
    }
}

extern "C" void kernel_launch(void* const* d_in, const int* in_sizes, int n_in,
                              void* d_out, int out_size, void* d_ws, size_t ws_size,
                              hipStream_t stream) {
    const int*   fi   = (const int*)d_in[0];     // [B, L, 1] int32 (sorted per b)
    const float* attr = (const float*)d_in[1];   // [B, L, D] float32
    float* out      = (float*)d_out;
    float* out_dist = out;                        // [B, L, K, 1]
    float* out_attr = out + (size_t)B_ * L_ * K_; // [B, L, K, D]

    fused_nbr_kernel<<<dim3(BLOCKS), dim3(256), 0, stream>>>(
        fi, attr, out_dist, out_attr);
}